// Round 9
// baseline (1126.563 us; speedup 1.0000x reference)
//
#include <hip/hip_runtime.h>

#define NSAMP 2048
#define NCONF 128
#define NMO   64
#define NE    16   // electrons per spin (matrix dim)

// Block = 256 threads = 2 samples x 128 configs.
// LDS: samples staged TRANSPOSED (column-major per (sample,spin) plane) with
// XOR swizzle on the 16B slot: word(c,r)=c*16+(((r>>2)^h(c))<<2)|(r&3),
// h(c)=(c^(c>>2))&3. One matrix column = 4 x ds_read_b128.
//
// Per thread: det(up)*det(dn) via LEFT-LOOKING Householder QR with:
//  * WY-PAIRED application: reflectors (k,k+1) applied jointly using the
//    precomputed cross-term zp[k/2] = V[k+1].V[k]; the two dots are
//    independent (2x ILP in the serial chain) and the update is one fused
//    pass: a[i] -= w0*V[k][i] + w1p*V[k+1][i].
//  * 1-column PREFETCH: column j+1's 4 ds_read_b128 issue before column j's
//    compute (double buffer buf[2][16], indices static after unroll).
// Register discipline: (256,1) only -- (256,2) spilled in rounds 2/4/7, and
// +32 live floats spilled even (256,1) in round 8. Net live delta here vs
// round 6 is ~+9 floats (buf +16, zp +7, cidx array dropped -14).
__global__ __launch_bounds__(256, 1)
void SlaterPooling_45543833207162_kernel(const float* __restrict__ x,
                                         const int*   __restrict__ cup,
                                         const int*   __restrict__ cdn,
                                         float*       __restrict__ out) {
  __shared__ float tile[4 * 64 * NE];   // 4 planes x 64 cols x 16 rows = 16 KB
  float4* tile4 = reinterpret_cast<float4*>(tile);

  // ---- stage 16 KB coalesced; write transposed + swizzled ----
  {
    const float4* src = reinterpret_cast<const float4*>(
        x + (size_t)blockIdx.x * 2 * (2 * NE * NMO));
#pragma unroll
    for (int k = 0; k < 4; ++k) {
      const int   f4 = threadIdx.x + k * 256;   // float4 index in block region
      const float4 v = src[f4];
      const int flat  = f4 * 4;                 // word index (row-major global)
      const int plane = flat >> 10;             // (s_local, spin) plane 0..3
      const int r     = (flat >> 6) & 15;       // row within plane
      const int c4    = (flat >> 2) & 15;       // c = 4*c4 + d
      const int rlo = r & 3, rhi = r >> 2;
      const float vv[4] = {v.x, v.y, v.z, v.w};
#pragma unroll
      for (int d = 0; d < 4; ++d) {
        const int cc = 4 * c4 + d;
        const int h  = (d ^ c4) & 3;            // == (cc ^ (cc>>2)) & 3
        tile[plane * 1024 + cc * NE + (((rhi ^ h) << 2) | rlo)] = vv[d];
      }
    }
  }
  __syncthreads();

  const int s_local = threadIdx.x >> 7;         // 0..1
  const int c       = threadIdx.x & 127;        // config index
  float result = 1.0f;

  // spin loop NOT unrolled: V, zp, buf reused across spins
#pragma unroll 1
  for (int spin = 0; spin < 2; ++spin) {
    const int* cfg = (spin ? cdn : cup) + c * NE;
    const float4* plane4 = tile4 + (s_local * 2 + spin) * 256;

    float V[NE - 1][NE];   // scaled reflector k in V[k][k..15]
    float zp[7];           // zp[k/2] = sum_i V[k+1][i]*V[k][i]  (k even)
    float buf[2][16];      // column double-buffer (static indices)
    float det = -1.0f;     // (-1)^15 from 15 reflectors

    // preload column 0
    {
      const int cj = cfg[0];
      const int h  = (cj ^ (cj >> 2)) & 3;
      const float4* col = plane4 + cj * 4;
      *reinterpret_cast<float4*>(&buf[0][ 0]) = col[0 ^ h];
      *reinterpret_cast<float4*>(&buf[0][ 4]) = col[1 ^ h];
      *reinterpret_cast<float4*>(&buf[0][ 8]) = col[2 ^ h];
      *reinterpret_cast<float4*>(&buf[0][12]) = col[3 ^ h];
    }

#pragma unroll
    for (int j = 0; j < NE; ++j) {
      // ---- prefetch column j+1 into the other buffer ----
      if (j + 1 < NE) {
        const int cj1 = cfg[j + 1];
        const int h1  = (cj1 ^ (cj1 >> 2)) & 3;
        const float4* col1 = plane4 + cj1 * 4;
        float* b = buf[(j + 1) & 1];
        *reinterpret_cast<float4*>(&b[ 0]) = col1[0 ^ h1];
        *reinterpret_cast<float4*>(&b[ 4]) = col1[1 ^ h1];
        *reinterpret_cast<float4*>(&b[ 8]) = col1[2 ^ h1];
        *reinterpret_cast<float4*>(&b[12]) = col1[3 ^ h1];
      }
      float* a = buf[j & 1];

      // ---- apply reflectors 0..j-1 in WY pairs (folds at compile time) ----
#pragma unroll
      for (int k = 0; k < NE - 1; k += 2) {
        if (k + 1 < j) {
          // pair (k, k+1): two independent dots, one fused update
          float d0a = 0.f, d0b = 0.f, d1a = 0.f, d1b = 0.f;
#pragma unroll
          for (int i = k; i < NE; ++i) {
            if (i & 1) d0b = fmaf(V[k][i], a[i], d0b);
            else       d0a = fmaf(V[k][i], a[i], d0a);
          }
#pragma unroll
          for (int i = k + 1; i < NE; ++i) {
            if (i & 1) d1b = fmaf(V[k + 1][i], a[i], d1b);
            else       d1a = fmaf(V[k + 1][i], a[i], d1a);
          }
          const float w0  = d0a + d0b;
          const float w1p = fmaf(-zp[k >> 1], w0, d1a + d1b);
          // i = k is never read again -> update i >= k+1 only
#pragma unroll
          for (int i = k + 1; i < NE; ++i)
            a[i] = fmaf(-w1p, V[k + 1][i], fmaf(-w0, V[k][i], a[i]));
        } else if (k < j) {
          // leftover single reflector (k == j-1, j odd)
          float da = 0.f, db = 0.f;
#pragma unroll
          for (int i = k; i < NE; ++i) {
            if (i & 1) db = fmaf(V[k][i], a[i], db);
            else       da = fmaf(V[k][i], a[i], da);
          }
          const float w = da + db;
#pragma unroll
          for (int i = k + 1; i < NE; ++i)
            a[i] = fmaf(-w, V[k][i], a[i]);
        }
      }

      // ---- form reflector j (or finish det on the last column) ----
      if (j < NE - 1) {
        float sa = 0.f, sb = 0.f, sc = 0.f, sd = 0.f;
#pragma unroll
        for (int i = j; i < NE; ++i) {
          const int m = i & 3;
          if      (m == 0) sa = fmaf(a[i], a[i], sa);
          else if (m == 1) sb = fmaf(a[i], a[i], sb);
          else if (m == 2) sc = fmaf(a[i], a[i], sc);
          else             sd = fmaf(a[i], a[i], sd);
        }
        const float s2    = (sa + sb) + (sc + sd);
        const float nrm   = __builtin_amdgcn_sqrtf(s2);
        const float ajj   = a[j];
        const float alpha = (ajj >= 0.0f) ? -nrm : nrm;     // R_jj
        const float vk    = ajj - alpha;                    // no cancellation
        const float vtv   = 2.0f * fmaf(-alpha, ajj, s2);   // v^T v
        // pre-scale v by sqrt(2/v'v): H = I - v v^T
        const float scale = 1.41421356237f * __builtin_amdgcn_rsqf(vtv);
        det *= alpha;
        V[j][j] = vk * scale;
#pragma unroll
        for (int i = j + 1; i < NE; ++i) V[j][i] = a[i] * scale;

        // cross-term for the WY pair (j-1, j), needed only for odd j
        if (j & 1) {
          float za = 0.f, zb = 0.f;
#pragma unroll
          for (int i = j; i < NE; ++i) {
            if (i & 1) zb = fmaf(V[j][i], V[j - 1][i], zb);
            else       za = fmaf(V[j][i], V[j - 1][i], za);
          }
          zp[(j - 1) >> 1] = za + zb;
        }
      } else {
        det *= a[NE - 1];   // R[15][15]
      }
    }
    result *= det;
  }

  // out[s*128 + c]
  out[(blockIdx.x * 2 + s_local) * NCONF + c] = result;
}

extern "C" void kernel_launch(void* const* d_in, const int* in_sizes, int n_in,
                              void* d_out, int out_size, void* d_ws, size_t ws_size,
                              hipStream_t stream) {
  const float* x   = (const float*)d_in[0];
  const int*   cup = (const int*)d_in[1];
  const int*   cdn = (const int*)d_in[2];
  float*       out = (float*)d_out;

  dim3 grid(NSAMP / 2), block(256);   // 1024 blocks, 2 samples each
  hipLaunchKernelGGL(SlaterPooling_45543833207162_kernel, grid, block, 0, stream,
                     x, cup, cdn, out);
}

// Round 10
// 61.097 us; speedup vs baseline: 18.4391x; 18.4391x over previous
//
#include <hip/hip_runtime.h>

#define NSAMP 2048
#define NCONF 128
#define NMO   64
#define NE    16   // electrons per spin (matrix dim)

// Block = 128 threads = 1 sample x 128 configs (2 waves).
// LDS #1: the sample's MO block staged TRANSPOSED (column-major per spin
//   plane) with XOR swizzle on the 16B slot: word(c,r)=c*16+(((r>>2)^h)<<2)
//   |(r&3), h=(c^(c>>2))&3. One matrix column = 4 x ds_read_b128.
// LDS #2: reflectors V[0..2] (45 floats, the largest/most-applied ones)
//   offloaded to vlds[slot][tid] -- slot-major so every access is
//   ds_read/write_b32 at base tid*4 + COMPILE-TIME immediate; consecutive
//   lanes hit consecutive words (2-way alias = free). This cuts the
//   register-resident V from 136 to 90 floats.
//
// Per thread: det(up)*det(dn) via LEFT-LOOKING Householder QR (round-6
// math, unchanged). Live set ~155 floats -> __launch_bounds__(128,2)
// (256-reg cap, 2 waves/SIMD) now has real headroom, unlike rounds 2/4/7
// (~220 live, spilled). LDS 8KB tile + 24KB V = 32KB -> 4 blocks/CU.
__global__ __launch_bounds__(128, 2)
void SlaterPooling_45543833207162_kernel(const float* __restrict__ x,
                                         const int*   __restrict__ cup,
                                         const int*   __restrict__ cdn,
                                         float*       __restrict__ out) {
  __shared__ float tile[2 * NE * NMO];   // 2 spin planes x 64 cols x 16 rows = 8 KB
  __shared__ float vlds[48 * 128];       // V[0..2]: slot (16k+i) major, tid minor
  float4* tile4 = reinterpret_cast<float4*>(tile);

  const int tid = threadIdx.x;           // 0..127 == config index

  // ---- stage 8 KB coalesced; write transposed + swizzled ----
  {
    const float4* src = reinterpret_cast<const float4*>(
        x + (size_t)blockIdx.x * (2 * NE * NMO));
#pragma unroll
    for (int k = 0; k < 4; ++k) {
      const int   f4 = tid + k * 128;     // float4 index in sample region
      const float4 v = src[f4];
      const int flat  = f4 * 4;           // word index (row-major global)
      const int plane = flat >> 10;       // spin plane 0..1
      const int r     = (flat >> 6) & 15; // row within plane
      const int c4    = (flat >> 2) & 15; // c = 4*c4 + d
      const int rlo = r & 3, rhi = r >> 2;
      const float vv[4] = {v.x, v.y, v.z, v.w};
#pragma unroll
      for (int d = 0; d < 4; ++d) {
        const int cc = 4 * c4 + d;
        const int h  = (d ^ c4) & 3;      // == (cc ^ (cc>>2)) & 3
        tile[plane * 1024 + cc * NE + (((rhi ^ h) << 2) | rlo)] = vv[d];
      }
    }
  }
  __syncthreads();

  float result = 1.0f;

  // spin loop NOT unrolled: Vr, vlds slots, column regs reused across spins
#pragma unroll 1
  for (int spin = 0; spin < 2; ++spin) {
    const int4* cfg4 = reinterpret_cast<const int4*>(
        (spin ? cdn : cup) + tid * NE);
    const int4 q0 = cfg4[0], q1 = cfg4[1], q2 = cfg4[2], q3 = cfg4[3];
    const int cidx[16] = {q0.x, q0.y, q0.z, q0.w,  q1.x, q1.y, q1.z, q1.w,
                          q2.x, q2.y, q2.z, q2.w,  q3.x, q3.y, q3.z, q3.w};

    const float4* plane4 = tile4 + spin * 256;

    float Vr[NE - 4][NE];  // register reflectors k=3..14 (Vr[k-3][k..15])
    float det = -1.0f;     // (-1)^15 from 15 reflectors

#pragma unroll
    for (int j = 0; j < NE; ++j) {
      // ---- column j: 4 x ds_read_b128 from the swizzled plane ----
      const int cj = cidx[j];
      const int h  = (cj ^ (cj >> 2)) & 3;
      const float4* col = plane4 + cj * 4;
      float a[NE];
      { const float4 t = col[0 ^ h]; a[ 0]=t.x; a[ 1]=t.y; a[ 2]=t.z; a[ 3]=t.w; }
      { const float4 t = col[1 ^ h]; a[ 4]=t.x; a[ 5]=t.y; a[ 6]=t.z; a[ 7]=t.w; }
      { const float4 t = col[2 ^ h]; a[ 8]=t.x; a[ 9]=t.y; a[10]=t.z; a[11]=t.w; }
      { const float4 t = col[3 ^ h]; a[12]=t.x; a[13]=t.y; a[14]=t.z; a[15]=t.w; }

      // ---- apply LDS reflectors k=0..2 (in order; k<j folds) ----
#pragma unroll
      for (int k = 0; k < 3; ++k) {
        if (k < j) {
          float v[NE];
#pragma unroll
          for (int i = k; i < NE; ++i)
            v[i] = vlds[(16 * k + i) * 128 + tid];
          float w4[4] = {0.f, 0.f, 0.f, 0.f};
#pragma unroll
          for (int i = k; i < NE; ++i)
            w4[i & 3] = fmaf(v[i], a[i], w4[i & 3]);
          const float w = (w4[0] + w4[1]) + (w4[2] + w4[3]);
          // i = k is never read again -> update i >= k+1 only
#pragma unroll
          for (int i = k + 1; i < NE; ++i)
            a[i] = fmaf(-w, v[i], a[i]);
        }
      }

      // ---- apply register reflectors k=3..j-1 ----
#pragma unroll
      for (int k = 3; k < NE - 1; ++k) {
        if (k < j) {
          float w4[4] = {0.f, 0.f, 0.f, 0.f};
#pragma unroll
          for (int i = k; i < NE; ++i)
            w4[i & 3] = fmaf(Vr[k - 3][i], a[i], w4[i & 3]);
          const float w = (w4[0] + w4[1]) + (w4[2] + w4[3]);
#pragma unroll
          for (int i = k + 1; i < NE; ++i)
            a[i] = fmaf(-w, Vr[k - 3][i], a[i]);
        }
      }

      // ---- form reflector j (or finish det on the last column) ----
      if (j < NE - 1) {
        float s4[4] = {0.f, 0.f, 0.f, 0.f};
#pragma unroll
        for (int i = j; i < NE; ++i)
          s4[i & 3] = fmaf(a[i], a[i], s4[i & 3]);
        const float s2    = (s4[0] + s4[1]) + (s4[2] + s4[3]);
        const float nrm   = __builtin_amdgcn_sqrtf(s2);
        const float ajj   = a[j];
        const float alpha = (ajj >= 0.0f) ? -nrm : nrm;     // R_jj
        const float vk    = ajj - alpha;                    // no cancellation
        const float vtv   = 2.0f * fmaf(-alpha, ajj, s2);   // v^T v
        // pre-scale v by sqrt(2/v'v): H = I - v v^T
        const float scale = 1.41421356237f * __builtin_amdgcn_rsqf(vtv);
        det *= alpha;
        if (j < 3) {
          vlds[(16 * j + j) * 128 + tid] = vk * scale;
#pragma unroll
          for (int i = j + 1; i < NE; ++i)
            vlds[(16 * j + i) * 128 + tid] = a[i] * scale;
        } else {
          Vr[j - 3][j] = vk * scale;
#pragma unroll
          for (int i = j + 1; i < NE; ++i)
            Vr[j - 3][i] = a[i] * scale;
        }
      } else {
        det *= a[NE - 1];   // R[15][15]
      }
    }
    result *= det;
  }

  out[blockIdx.x * NCONF + tid] = result;   // out[s*128 + c]
}

extern "C" void kernel_launch(void* const* d_in, const int* in_sizes, int n_in,
                              void* d_out, int out_size, void* d_ws, size_t ws_size,
                              hipStream_t stream) {
  const float* x   = (const float*)d_in[0];
  const int*   cup = (const int*)d_in[1];
  const int*   cdn = (const int*)d_in[2];
  float*       out = (float*)d_out;

  dim3 grid(NSAMP), block(128);   // 2048 blocks: 1 sample x 128 configs
  hipLaunchKernelGGL(SlaterPooling_45543833207162_kernel, grid, block, 0, stream,
                     x, cup, cdn, out);
}